// Round 6
// baseline (1241.937 us; speedup 1.0000x reference)
//
#include <hip/hip_runtime.h>
#include <math.h>

#define NN 20000     // nodes
#define NE 320000    // edges
#define HD 256       // hidden dim
#define EDIM 64      // edge feature dim
#define DIN 576      // 2H + ED

typedef __attribute__((ext_vector_type(4))) _Float16 h4;
typedef __attribute__((ext_vector_type(8))) _Float16 h8;
typedef __attribute__((ext_vector_type(4))) float f32x4;

// fragment order: frag(cf, ks, l, j) = W[cf*16 + (l&15)][ks*32 + (l>>4)*8 + j]
__device__ _Float16 g_W1cf[16 * 2 * 64 * 8];    // W1 eattr part (A-operand, M=hid cols)
__device__ _Float16 g_W12f[32 * 8 * 64 * 8];    // [W1a;W1b] for pre kernel (B-operand)
__device__ _Float16 g_Wrzf[32 * 16 * 64 * 8];   // GRU r,z: K=512 = [Wfold | W_hh]
__device__ _Float16 g_Wnxf[16 * 8 * 64 * 8];    // GRU n-gate, S side (Wfold rows 512..767)
__device__ _Float16 g_Wnhf[16 * 8 * 64 * 8];    // GRU n-gate, h side (W_hh rows 512..767)
__device__ float    g_Wib2[768];                // W_ih @ b2
__device__ _Float16 g_pre[(size_t)NN * 512];    // [node][pre1(256) | pre2(256)]

__device__ __forceinline__ h4 f2h4(float4 v) {
  return (h4){(_Float16)v.x, (_Float16)v.y, (_Float16)v.z, (_Float16)v.w};
}
__device__ __forceinline__ h8 f2h8(float4 a, float4 b) {
  return (h8){(_Float16)a.x, (_Float16)a.y, (_Float16)a.z, (_Float16)a.w,
              (_Float16)b.x, (_Float16)b.y, (_Float16)b.z, (_Float16)b.w};
}

// -------------------- weight repack (inputs only) --------------------
// groups: W1cf 32 | W12f 256 | Wrzf(ks>=8, W_hh part) 256 | Wnhf 128  => 672
__global__ __launch_bounds__(256) void cvt_kernel(const float* __restrict__ W1,
                                                  const float* __restrict__ W_hh) {
  const int idx = blockIdx.x * 256 + threadIdx.x;
  const int g = idx >> 6, l = idx & 63;
  const int r16 = l & 15, koff = (l >> 4) * 8;
  const float* src; _Float16* dst;
  if (g < 32) {                                   // W1cf: cf<16, ks<2 (k = 512+...)
    const int cf = g >> 1, ks = g & 1;
    src = &W1[(size_t)(cf * 16 + r16) * DIN + 512 + ks * 32 + koff];
    dst = &g_W1cf[(size_t)(cf * 2 + ks) * 512 + l * 8];
  } else if (g < 288) {                           // W12f: cf<32, ks<8
    const int gg = g - 32, cf = gg >> 3, ks = gg & 7;
    src = (cf < 16) ? &W1[(size_t)(cf * 16 + r16) * DIN + ks * 32 + koff]
                    : &W1[(size_t)((cf - 16) * 16 + r16) * DIN + 256 + ks * 32 + koff];
    dst = &g_W12f[(size_t)(cf * 8 + ks) * 512 + l * 8];
  } else if (g < 544) {                           // Wrzf ks in [8,16): W_hh r,z rows
    const int gg = g - 288, cf = gg >> 3, ks = 8 + (gg & 7);
    const int row = (cf < 16) ? cf * 16 + r16 : 256 + (cf - 16) * 16 + r16;
    src = &W_hh[(size_t)row * HD + (ks - 8) * 32 + koff];
    dst = &g_Wrzf[(size_t)(cf * 16 + ks) * 512 + l * 8];
  } else {                                        // Wnhf: W_hh rows 512..767
    const int gg = g - 544, cf = gg >> 3, ks = gg & 7;
    src = &W_hh[(size_t)(512 + cf * 16 + r16) * HD + ks * 32 + koff];
    dst = &g_Wnhf[(size_t)(cf * 8 + ks) * 512 + l * 8];
  }
#pragma unroll
  for (int j = 0; j < 8; ++j) dst[j] = (_Float16)src[j];
}

// -------------------- Wfold = W_ih @ W2, Wib2 = W_ih @ b2 --------------------
// block r (768), thread c (256): Wfold[r][c] = sum_m W_ih[r][m] * W2[m][c]
__global__ __launch_bounds__(256) void fold_kernel(const float* __restrict__ W_ih,
                                                   const float* __restrict__ W2,
                                                   const float* __restrict__ b2) {
  const int r = blockIdx.x, c = threadIdx.x;
  const float* wr = W_ih + (size_t)r * HD;
  float acc = 0.f;
  for (int m = 0; m < HD; ++m) acc += wr[m] * W2[(size_t)m * HD + c];
  const int ks = c >> 5, lg = (c >> 3) & 3, j = c & 7;
  const int l = lg * 16 + (r & 15);
  if (r < 512) {
    const int cf = (r < 256) ? (r >> 4) : (16 + ((r - 256) >> 4));
    g_Wrzf[(size_t)((cf * 16 + ks) * 64 + l) * 8 + j] = (_Float16)acc;
  } else {
    const int cf = (r - 512) >> 4;
    g_Wnxf[(size_t)((cf * 8 + ks) * 64 + l) * 8 + j] = (_Float16)acc;
  }
  if (c == 0) {
    float a2 = 0.f;
    for (int m = 0; m < HD; ++m) a2 += wr[m] * b2[m];
    g_Wib2[r] = a2;
  }
}

// -------------------- pre kernel: pre12 = h @ [W1a|W1b]^T --------------------
#define PSTR 264
__global__ __launch_bounds__(256, 4) void pre_kernel(const float* __restrict__ h) {
  __shared__ _Float16 A[32 * PSTR];   // 16.9 KB
  const int t = threadIdx.x, w = t >> 6, l = t & 63;
  const int l15 = l & 15, lg = l >> 4;
  const int nb = blockIdx.x * 32;

  const int row = t >> 3, c8 = t & 7;
#pragma unroll
  for (int i = 0; i < 8; ++i) {
    const int col4 = c8 + i * 8;
    float4 v = ((const float4*)(h + (size_t)(nb + row) * HD))[col4];
    *(h4*)&A[row * PSTR + col4 * 4] = f2h4(v);
  }
  __syncthreads();

  f32x4 acc[2][8];
#pragma unroll
  for (int m = 0; m < 2; ++m)
#pragma unroll
    for (int n = 0; n < 8; ++n) acc[m][n] = (f32x4){0.f, 0.f, 0.f, 0.f};

  for (int ks = 0; ks < 8; ++ks) {
    h8 a[2];
#pragma unroll
    for (int m = 0; m < 2; ++m)
      a[m] = *(const h8*)&A[(m * 16 + l15) * PSTR + ks * 32 + lg * 8];
#pragma unroll
    for (int n = 0; n < 8; ++n) {
      const h8 b = *(const h8*)&g_W12f[(size_t)((w * 8 + n) * 8 + ks) * 512 + l * 8];
#pragma unroll
      for (int m = 0; m < 2; ++m)
        acc[m][n] = __builtin_amdgcn_mfma_f32_16x16x32_f16(a[m], b, acc[m][n], 0, 0, 0);
    }
  }

#pragma unroll
  for (int m = 0; m < 2; ++m)
#pragma unroll
    for (int n = 0; n < 8; ++n) {
      const int col = w * 128 + n * 16 + l15;
#pragma unroll
      for (int r = 0; r < 4; ++r)
        g_pre[(size_t)(nb + m * 16 + lg * 4 + r) * 512 + col] = (_Float16)acc[m][n][r];
    }
}

// -------------------- edge kernel: eattr GEMM (transposed) + pre-add + scatter ----
// 64 edges/block, no LDS. Wave w owns hid cols [64w,64w+64) (M), all 64 edges (N).
// C/D: col(lane&15)=edge sub, row=(lane>>4)*4+r -> hid col c = w*64+m*16+lg*4+r.
__global__ __launch_bounds__(256) void edge_kernel(
    const float* __restrict__ eattr, const int* __restrict__ ei,
    const float* __restrict__ b1, float* __restrict__ S, int* __restrict__ deg)
{
  const int t = threadIdx.x, w = t >> 6, l = t & 63;
  const int l15 = l & 15, lg = l >> 4;
  const int e0 = blockIdx.x * 64;

  if (t < 64) atomicAdd(&deg[ei[e0 + t]], 1);

  int re[4], ce[4];
#pragma unroll
  for (int n = 0; n < 4; ++n) {
    re[n] = ei[e0 + n * 16 + l15];
    ce[n] = ei[NE + e0 + n * 16 + l15];
  }

  f32x4 acc[4][4];
#pragma unroll
  for (int m = 0; m < 4; ++m)
#pragma unroll
    for (int n = 0; n < 4; ++n) acc[m][n] = (f32x4){0.f, 0.f, 0.f, 0.f};

#pragma unroll
  for (int ks = 0; ks < 2; ++ks) {
    h8 af[4], bf[4];
#pragma unroll
    for (int m = 0; m < 4; ++m)
      af[m] = *(const h8*)&g_W1cf[(size_t)((w * 4 + m) * 2 + ks) * 512 + l * 8];
#pragma unroll
    for (int n = 0; n < 4; ++n) {
      const float* ep = eattr + (size_t)(e0 + n * 16 + l15) * EDIM + ks * 32 + lg * 8;
      bf[n] = f2h8(((const float4*)ep)[0], ((const float4*)ep)[1]);
    }
#pragma unroll
    for (int m = 0; m < 4; ++m)
#pragma unroll
      for (int n = 0; n < 4; ++n)
        acc[m][n] = __builtin_amdgcn_mfma_f32_16x16x32_f16(af[m], bf[n], acc[m][n], 0, 0, 0);
  }

  f32x4 b1v[4];
#pragma unroll
  for (int m = 0; m < 4; ++m)
    b1v[m] = *(const f32x4*)&b1[w * 64 + m * 16 + lg * 4];

#pragma unroll
  for (int n = 0; n < 4; ++n) {
    const _Float16* p1 = g_pre + (size_t)re[n] * 512;
    const _Float16* p2 = g_pre + (size_t)ce[n] * 512 + 256;
    float* srow = S + (size_t)re[n] * HD;
#pragma unroll
    for (int m = 0; m < 4; ++m) {
      const int c0 = w * 64 + m * 16 + lg * 4;
      const h4 q1 = *(const h4*)&p1[c0];
      const h4 q2 = *(const h4*)&p2[c0];
#pragma unroll
      for (int r = 0; r < 4; ++r) {
        float v = acc[m][n][r] + (float)q1[r] + (float)q2[r] + b1v[m][r];
        v = v > 0.f ? v : 0.f;
        unsafeAtomicAdd(&srow[c0 + r], v);
      }
    }
  }
}

// -------------------- node kernel: fused W2-fold GRU --------------------
#define ASTRIDE 264
__global__ __launch_bounds__(256, 4) void node_kernel(
    const float* __restrict__ h, const float* __restrict__ S,
    const int* __restrict__ deg,
    const float* __restrict__ b_ih, const float* __restrict__ b_hh,
    float* __restrict__ out)
{
  __shared__ _Float16 A[64 * ASTRIDE];

  const int t = threadIdx.x, w = t >> 6, l = t & 63;
  const int l15 = l & 15, lg = l >> 4;
  const int nb = blockIdx.x * 64;
  const int c0 = blockIdx.y * 64;
  const int cf0 = c0 >> 4;

  f32x4 ar[4], az[4], ax[4], ah[4];
#pragma unroll
  for (int n = 0; n < 4; ++n) {
    ar[n] = (f32x4){0.f, 0.f, 0.f, 0.f}; az[n] = (f32x4){0.f, 0.f, 0.f, 0.f};
    ax[n] = (f32x4){0.f, 0.f, 0.f, 0.f}; ah[n] = (f32x4){0.f, 0.f, 0.f, 0.f};
  }

  const int afrag_base = (w * 16 + l15) * ASTRIDE + lg * 8;

#pragma unroll
  for (int s = 0; s < 2; ++s) {
    __syncthreads();
    const float* src = s == 0 ? S : h;
#pragma unroll
    for (int i = 0; i < 16; ++i) {
      const int e = i * 4 + w;
      int node = nb + e; if (node >= NN) node = NN - 1;
      float4 v = ((const float4*)(src + (size_t)node * HD))[l];
      *(h4*)&A[e * ASTRIDE + l * 4] = f2h4(v);
    }
    __syncthreads();
    for (int ks = 0; ks < 8; ++ks) {
      const int ksg = s * 8 + ks;
      const h8 a = *(const h8*)&A[afrag_base + ks * 32];
      h8 br[4], bz[4], bn[4];
#pragma unroll
      for (int n = 0; n < 4; ++n) {
        br[n] = *(const h8*)&g_Wrzf[(size_t)(((cf0 + n) * 16 + ksg) * 64 + l) * 8];
        bz[n] = *(const h8*)&g_Wrzf[(size_t)(((16 + cf0 + n) * 16 + ksg) * 64 + l) * 8];
        bn[n] = (s == 0)
          ? *(const h8*)&g_Wnxf[(size_t)(((cf0 + n) * 8 + ks) * 64 + l) * 8]
          : *(const h8*)&g_Wnhf[(size_t)(((cf0 + n) * 8 + ks) * 64 + l) * 8];
      }
#pragma unroll
      for (int n = 0; n < 4; ++n) {
        ar[n] = __builtin_amdgcn_mfma_f32_16x16x32_f16(a, br[n], ar[n], 0, 0, 0);
        az[n] = __builtin_amdgcn_mfma_f32_16x16x32_f16(a, bz[n], az[n], 0, 0, 0);
        if (s == 0) ax[n] = __builtin_amdgcn_mfma_f32_16x16x32_f16(a, bn[n], ax[n], 0, 0, 0);
        else        ah[n] = __builtin_amdgcn_mfma_f32_16x16x32_f16(a, bn[n], ah[n], 0, 0, 0);
      }
    }
  }

#pragma unroll
  for (int r = 0; r < 4; ++r) {
    const int node = nb + w * 16 + lg * 4 + r;
    if (node >= NN) continue;
    const float df = (float)deg[node];
#pragma unroll
    for (int n = 0; n < 4; ++n) {
      const int c = c0 + n * 16 + l15;
      const float rg = 1.f / (1.f + __expf(-(ar[n][r] + df * g_Wib2[c] + b_ih[c] + b_hh[c])));
      const float zg = 1.f / (1.f + __expf(-(az[n][r] + df * g_Wib2[HD + c] + b_ih[HD + c] + b_hh[HD + c])));
      const float ng = tanhf(ax[n][r] + df * g_Wib2[2 * HD + c] + b_ih[2 * HD + c]
                             + rg * (ah[n][r] + b_hh[2 * HD + c]));
      const float hv = h[(size_t)node * HD + c];
      out[(size_t)node * HD + c] = (1.f - zg) * ng + zg * hv;
    }
  }
}

extern "C" void kernel_launch(void* const* d_in, const int* in_sizes, int n_in,
                              void* d_out, int out_size, void* d_ws, size_t ws_size,
                              hipStream_t stream)
{
  const float* h     = (const float*)d_in[0];
  const int*   ei    = (const int*)d_in[1];
  const float* eattr = (const float*)d_in[2];
  const float* W1    = (const float*)d_in[3];
  // d_in[4] = b1, d_in[5] = W2, d_in[6] = b2
  const float* b1    = (const float*)d_in[4];
  const float* W2    = (const float*)d_in[5];
  const float* b2    = (const float*)d_in[6];
  const float* W_ih  = (const float*)d_in[7];
  const float* b_ih  = (const float*)d_in[8];
  const float* W_hh  = (const float*)d_in[9];
  const float* b_hh  = (const float*)d_in[10];
  float* out = (float*)d_out;

  float* S  = (float*)d_ws;                                 // [NN][HD] f32
  int*  deg = (int*)((char*)d_ws + (size_t)NN * HD * 4);    // [NN] i32

  hipMemsetAsync(d_ws, 0, (size_t)NN * HD * 4 + (size_t)NN * 4, stream);
  cvt_kernel<<<168, 256, 0, stream>>>(W1, W_hh);
  fold_kernel<<<768, 256, 0, stream>>>(W_ih, W2, b2);
  pre_kernel<<<NN / 32, 256, 0, stream>>>(h);
  edge_kernel<<<NE / 64, 256, 0, stream>>>(eattr, ei, b1, S, deg);
  node_kernel<<<dim3((NN + 63) / 64, HD / 64), 256, 0, stream>>>(h, S, deg, b_ih, b_hh, out);
}

// Round 7
// 525.337 us; speedup vs baseline: 2.3641x; 2.3641x over previous
//
#include <hip/hip_runtime.h>
#include <math.h>

#define NN 20000     // nodes
#define NE 320000    // edges
#define HD 256       // hidden dim
#define EDIM 64      // edge feature dim
#define DIN 576      // 2H + ED

typedef __attribute__((ext_vector_type(4))) _Float16 h4;
typedef __attribute__((ext_vector_type(8))) _Float16 h8;
typedef __attribute__((ext_vector_type(4))) float f32x4;

// fragment order: frag(cf, ks, l, j) = W[cf*16 + (l&15)][ks*32 + (l>>4)*8 + j]
__device__ _Float16 g_W1cf[16 * 2 * 64 * 8];    // W1 eattr part (cols as frag rows)
__device__ _Float16 g_W12f[32 * 8 * 64 * 8];    // [W1a;W1b] for pre kernel (B-operand)
__device__ _Float16 g_Wrzf[32 * 16 * 64 * 8];   // GRU r,z: K=512 = [Wfold | W_hh]
__device__ _Float16 g_Wnxf[16 * 8 * 64 * 8];    // GRU n-gate, S side (Wfold rows 512..767)
__device__ _Float16 g_Wnhf[16 * 8 * 64 * 8];    // GRU n-gate, h side (W_hh rows 512..767)
__device__ float    g_Wib2[768];                // W_ih @ b2
__device__ _Float16 g_pre[(size_t)NN * 512];    // [node][pre1(256) | pre2(256)]

__device__ __forceinline__ h4 f2h4(float4 v) {
  return (h4){(_Float16)v.x, (_Float16)v.y, (_Float16)v.z, (_Float16)v.w};
}
__device__ __forceinline__ h8 f2h8(float4 a, float4 b) {
  return (h8){(_Float16)a.x, (_Float16)a.y, (_Float16)a.z, (_Float16)a.w,
              (_Float16)b.x, (_Float16)b.y, (_Float16)b.z, (_Float16)b.w};
}

// -------------------- weight repack (inputs only) --------------------
// groups: W1cf 32 | W12f 256 | Wrzf(ks>=8, W_hh part) 256 | Wnhf 128  => 672
__global__ __launch_bounds__(256) void cvt_kernel(const float* __restrict__ W1,
                                                  const float* __restrict__ W_hh) {
  const int idx = blockIdx.x * 256 + threadIdx.x;
  const int g = idx >> 6, l = idx & 63;
  const int r16 = l & 15, koff = (l >> 4) * 8;
  const float* src; _Float16* dst;
  if (g < 32) {                                   // W1cf: cf<16, ks<2 (k = 512+...)
    const int cf = g >> 1, ks = g & 1;
    src = &W1[(size_t)(cf * 16 + r16) * DIN + 512 + ks * 32 + koff];
    dst = &g_W1cf[(size_t)(cf * 2 + ks) * 512 + l * 8];
  } else if (g < 288) {                           // W12f: cf<32, ks<8
    const int gg = g - 32, cf = gg >> 3, ks = gg & 7;
    src = (cf < 16) ? &W1[(size_t)(cf * 16 + r16) * DIN + ks * 32 + koff]
                    : &W1[(size_t)((cf - 16) * 16 + r16) * DIN + 256 + ks * 32 + koff];
    dst = &g_W12f[(size_t)(cf * 8 + ks) * 512 + l * 8];
  } else if (g < 544) {                           // Wrzf ks in [8,16): W_hh r,z rows
    const int gg = g - 288, cf = gg >> 3, ks = 8 + (gg & 7);
    const int row = (cf < 16) ? cf * 16 + r16 : 256 + (cf - 16) * 16 + r16;
    src = &W_hh[(size_t)row * HD + (ks - 8) * 32 + koff];
    dst = &g_Wrzf[(size_t)(cf * 16 + ks) * 512 + l * 8];
  } else {                                        // Wnhf: W_hh rows 512..767
    const int gg = g - 544, cf = gg >> 3, ks = gg & 7;
    src = &W_hh[(size_t)(512 + cf * 16 + r16) * HD + ks * 32 + koff];
    dst = &g_Wnhf[(size_t)(cf * 8 + ks) * 512 + l * 8];
  }
#pragma unroll
  for (int j = 0; j < 8; ++j) dst[j] = (_Float16)src[j];
}

// -------------------- Wfold = W_ih @ W2, Wib2 = W_ih @ b2 --------------------
__global__ __launch_bounds__(256) void fold_kernel(const float* __restrict__ W_ih,
                                                   const float* __restrict__ W2,
                                                   const float* __restrict__ b2) {
  const int r = blockIdx.x, c = threadIdx.x;
  const float* wr = W_ih + (size_t)r * HD;
  float acc = 0.f;
  for (int m = 0; m < HD; ++m) acc += wr[m] * W2[(size_t)m * HD + c];
  const int ks = c >> 5, lg = (c >> 3) & 3, j = c & 7;
  const int l = lg * 16 + (r & 15);
  if (r < 512) {
    const int cf = (r < 256) ? (r >> 4) : (16 + ((r - 256) >> 4));
    g_Wrzf[(size_t)((cf * 16 + ks) * 64 + l) * 8 + j] = (_Float16)acc;
  } else {
    const int cf = (r - 512) >> 4;
    g_Wnxf[(size_t)((cf * 8 + ks) * 64 + l) * 8 + j] = (_Float16)acc;
  }
  if (c == 0) {
    float a2 = 0.f;
    for (int m = 0; m < HD; ++m) a2 += wr[m] * b2[m];
    g_Wib2[r] = a2;
  }
}

// -------------------- pre kernel: pre12 = h @ [W1a|W1b]^T --------------------
#define PSTR 264
__global__ __launch_bounds__(256, 4) void pre_kernel(const float* __restrict__ h) {
  __shared__ _Float16 A[32 * PSTR];   // 16.9 KB
  const int t = threadIdx.x, w = t >> 6, l = t & 63;
  const int l15 = l & 15, lg = l >> 4;
  const int nb = blockIdx.x * 32;

  const int row = t >> 3, c8 = t & 7;
#pragma unroll
  for (int i = 0; i < 8; ++i) {
    const int col4 = c8 + i * 8;
    float4 v = ((const float4*)(h + (size_t)(nb + row) * HD))[col4];
    *(h4*)&A[row * PSTR + col4 * 4] = f2h4(v);
  }
  __syncthreads();

  f32x4 acc[2][8];
#pragma unroll
  for (int m = 0; m < 2; ++m)
#pragma unroll
    for (int n = 0; n < 8; ++n) acc[m][n] = (f32x4){0.f, 0.f, 0.f, 0.f};

  for (int ks = 0; ks < 8; ++ks) {
    h8 a[2];
#pragma unroll
    for (int m = 0; m < 2; ++m)
      a[m] = *(const h8*)&A[(m * 16 + l15) * PSTR + ks * 32 + lg * 8];
#pragma unroll
    for (int n = 0; n < 8; ++n) {
      const h8 b = *(const h8*)&g_W12f[(size_t)((w * 8 + n) * 8 + ks) * 512 + l * 8];
#pragma unroll
      for (int m = 0; m < 2; ++m)
        acc[m][n] = __builtin_amdgcn_mfma_f32_16x16x32_f16(a[m], b, acc[m][n], 0, 0, 0);
    }
  }

#pragma unroll
  for (int m = 0; m < 2; ++m)
#pragma unroll
    for (int n = 0; n < 8; ++n) {
      const int col = w * 128 + n * 16 + l15;
#pragma unroll
      for (int r = 0; r < 4; ++r)
        g_pre[(size_t)(nb + m * 16 + lg * 4 + r) * 512 + col] = (_Float16)acc[m][n][r];
    }
}

// -------------------- edge kernel: eattr GEMM + pre-add + coalesced scatter ----
// 64 edges/block, no LDS. A = eattr (edges as M-rows), B = W1c (wave w owns
// hid cols [64w,64w+64)). C/D: col=lane&15 -> hid col (consecutive per 16-lane
// group), row -> edge. Atomic instr touches 4 lines (R4 pattern), not 64.
__global__ __launch_bounds__(256) void edge_kernel(
    const float* __restrict__ eattr, const int* __restrict__ ei,
    const float* __restrict__ b1, float* __restrict__ S, int* __restrict__ deg)
{
  const int t = threadIdx.x, w = t >> 6, l = t & 63;
  const int l15 = l & 15, lg = l >> 4;
  const int e0 = blockIdx.x * 64;

  if (t < 64) atomicAdd(&deg[ei[e0 + t]], 1);

  f32x4 acc[4][4];
#pragma unroll
  for (int m = 0; m < 4; ++m)
#pragma unroll
    for (int n = 0; n < 4; ++n) acc[m][n] = (f32x4){0.f, 0.f, 0.f, 0.f};

#pragma unroll
  for (int ks = 0; ks < 2; ++ks) {
    h8 a[4], b[4];
#pragma unroll
    for (int m = 0; m < 4; ++m) {
      const float* ep = eattr + (size_t)(e0 + m * 16 + l15) * EDIM + ks * 32 + lg * 8;
      a[m] = f2h8(((const float4*)ep)[0], ((const float4*)ep)[1]);
    }
#pragma unroll
    for (int n = 0; n < 4; ++n)
      b[n] = *(const h8*)&g_W1cf[(size_t)((w * 4 + n) * 2 + ks) * 512 + l * 8];
#pragma unroll
    for (int m = 0; m < 4; ++m)
#pragma unroll
      for (int n = 0; n < 4; ++n)
        acc[m][n] = __builtin_amdgcn_mfma_f32_16x16x32_f16(a[m], b[n], acc[m][n], 0, 0, 0);
  }

  float b1v[4];
#pragma unroll
  for (int n = 0; n < 4; ++n) b1v[n] = b1[w * 64 + n * 16 + l15];

#pragma unroll
  for (int m = 0; m < 4; ++m) {
#pragma unroll
    for (int r = 0; r < 4; ++r) {
      const int e = m * 16 + lg * 4 + r;
      const int re = ei[e0 + e];
      const int ce = ei[NE + e0 + e];
      const _Float16* p1 = g_pre + (size_t)re * 512;
      const _Float16* p2 = g_pre + (size_t)ce * 512 + 256;
      float* srow = S + (size_t)re * HD;
#pragma unroll
      for (int n = 0; n < 4; ++n) {
        const int c = w * 64 + n * 16 + l15;
        float v = acc[m][n][r] + (float)p1[c] + (float)p2[c] + b1v[n];
        v = v > 0.f ? v : 0.f;
        unsafeAtomicAdd(&srow[c], v);
      }
    }
  }
}

// -------------------- node kernel: fused W2-fold GRU --------------------
#define ASTRIDE 264
__global__ __launch_bounds__(256, 4) void node_kernel(
    const float* __restrict__ h, const float* __restrict__ S,
    const int* __restrict__ deg,
    const float* __restrict__ b_ih, const float* __restrict__ b_hh,
    float* __restrict__ out)
{
  __shared__ _Float16 A[64 * ASTRIDE];

  const int t = threadIdx.x, w = t >> 6, l = t & 63;
  const int l15 = l & 15, lg = l >> 4;
  const int nb = blockIdx.x * 64;
  const int c0 = blockIdx.y * 64;
  const int cf0 = c0 >> 4;

  f32x4 ar[4], az[4], ax[4], ah[4];
#pragma unroll
  for (int n = 0; n < 4; ++n) {
    ar[n] = (f32x4){0.f, 0.f, 0.f, 0.f}; az[n] = (f32x4){0.f, 0.f, 0.f, 0.f};
    ax[n] = (f32x4){0.f, 0.f, 0.f, 0.f}; ah[n] = (f32x4){0.f, 0.f, 0.f, 0.f};
  }

  const int afrag_base = (w * 16 + l15) * ASTRIDE + lg * 8;

#pragma unroll
  for (int s = 0; s < 2; ++s) {
    __syncthreads();
    const float* src = s == 0 ? S : h;
#pragma unroll
    for (int i = 0; i < 16; ++i) {
      const int e = i * 4 + w;
      int node = nb + e; if (node >= NN) node = NN - 1;
      float4 v = ((const float4*)(src + (size_t)node * HD))[l];
      *(h4*)&A[e * ASTRIDE + l * 4] = f2h4(v);
    }
    __syncthreads();
    for (int ks = 0; ks < 8; ++ks) {
      const int ksg = s * 8 + ks;
      const h8 a = *(const h8*)&A[afrag_base + ks * 32];
      h8 br[4], bz[4], bn[4];
#pragma unroll
      for (int n = 0; n < 4; ++n) {
        br[n] = *(const h8*)&g_Wrzf[(size_t)(((cf0 + n) * 16 + ksg) * 64 + l) * 8];
        bz[n] = *(const h8*)&g_Wrzf[(size_t)(((16 + cf0 + n) * 16 + ksg) * 64 + l) * 8];
        bn[n] = (s == 0)
          ? *(const h8*)&g_Wnxf[(size_t)(((cf0 + n) * 8 + ks) * 64 + l) * 8]
          : *(const h8*)&g_Wnhf[(size_t)(((cf0 + n) * 8 + ks) * 64 + l) * 8];
      }
#pragma unroll
      for (int n = 0; n < 4; ++n) {
        ar[n] = __builtin_amdgcn_mfma_f32_16x16x32_f16(a, br[n], ar[n], 0, 0, 0);
        az[n] = __builtin_amdgcn_mfma_f32_16x16x32_f16(a, bz[n], az[n], 0, 0, 0);
        if (s == 0) ax[n] = __builtin_amdgcn_mfma_f32_16x16x32_f16(a, bn[n], ax[n], 0, 0, 0);
        else        ah[n] = __builtin_amdgcn_mfma_f32_16x16x32_f16(a, bn[n], ah[n], 0, 0, 0);
      }
    }
  }

#pragma unroll
  for (int r = 0; r < 4; ++r) {
    const int node = nb + w * 16 + lg * 4 + r;
    if (node >= NN) continue;
    const float df = (float)deg[node];
#pragma unroll
    for (int n = 0; n < 4; ++n) {
      const int c = c0 + n * 16 + l15;
      const float rg = 1.f / (1.f + __expf(-(ar[n][r] + df * g_Wib2[c] + b_ih[c] + b_hh[c])));
      const float zg = 1.f / (1.f + __expf(-(az[n][r] + df * g_Wib2[HD + c] + b_ih[HD + c] + b_hh[HD + c])));
      const float ng = tanhf(ax[n][r] + df * g_Wib2[2 * HD + c] + b_ih[2 * HD + c]
                             + rg * (ah[n][r] + b_hh[2 * HD + c]));
      const float hv = h[(size_t)node * HD + c];
      out[(size_t)node * HD + c] = (1.f - zg) * ng + zg * hv;
    }
  }
}

extern "C" void kernel_launch(void* const* d_in, const int* in_sizes, int n_in,
                              void* d_out, int out_size, void* d_ws, size_t ws_size,
                              hipStream_t stream)
{
  const float* h     = (const float*)d_in[0];
  const int*   ei    = (const int*)d_in[1];
  const float* eattr = (const float*)d_in[2];
  const float* W1    = (const float*)d_in[3];
  const float* b1    = (const float*)d_in[4];
  const float* W2    = (const float*)d_in[5];
  const float* b2    = (const float*)d_in[6];
  const float* W_ih  = (const float*)d_in[7];
  const float* b_ih  = (const float*)d_in[8];
  const float* W_hh  = (const float*)d_in[9];
  const float* b_hh  = (const float*)d_in[10];
  float* out = (float*)d_out;

  float* S  = (float*)d_ws;                                 // [NN][HD] f32
  int*  deg = (int*)((char*)d_ws + (size_t)NN * HD * 4);    // [NN] i32

  hipMemsetAsync(d_ws, 0, (size_t)NN * HD * 4 + (size_t)NN * 4, stream);
  cvt_kernel<<<168, 256, 0, stream>>>(W1, W_hh);
  fold_kernel<<<768, 256, 0, stream>>>(W_ih, W2, b2);
  pre_kernel<<<NN / 32, 256, 0, stream>>>(h);
  edge_kernel<<<NE / 64, 256, 0, stream>>>(eattr, ei, b1, S, deg);
  node_kernel<<<dim3((NN + 63) / 64, HD / 64), 256, 0, stream>>>(h, S, deg, b_ih, b_hh, out);
}

// Round 8
// 435.482 us; speedup vs baseline: 2.8519x; 1.2063x over previous
//
#include <hip/hip_runtime.h>
#include <math.h>

#define NN 20000     // nodes
#define NE 320000    // edges
#define HD 256       // hidden dim
#define EDIM 64      // edge feature dim
#define DIN 576      // 2H + ED

typedef __attribute__((ext_vector_type(4))) _Float16 h4;
typedef __attribute__((ext_vector_type(8))) _Float16 h8;
typedef __attribute__((ext_vector_type(4))) float f32x4;

// fragment order: frag(cf, ks, l, j) = W[cf*16 + (l&15)][ks*32 + (l>>4)*8 + j]
__device__ _Float16 g_W1cf[16 * 2 * 64 * 8];    // W1 eattr part
__device__ _Float16 g_W12f[32 * 8 * 64 * 8];    // [W1a;W1b] for pre kernel (B-operand)
__device__ _Float16 g_Wrzf[32 * 16 * 64 * 8];   // GRU r,z: K=512 = [Wfold | W_hh]
__device__ _Float16 g_Wnxf[16 * 8 * 64 * 8];    // GRU n-gate, S side (Wfold rows 512..767)
__device__ _Float16 g_Wnhf[16 * 8 * 64 * 8];    // GRU n-gate, h side (W_hh rows 512..767)
__device__ float    g_Wib2[768];                // W_ih @ b2
__device__ _Float16 g_pre[(size_t)NN * 512];    // [node][pre1(256) | pre2(256)]
__device__ _Float16 g_eterm[(size_t)NE * 256];  // W1c @ eattr, per edge (164 MB)
__device__ int      g_rowptr[NN + 1];
__device__ int      g_cursor[NN];
__device__ int      g_perm[NE];
__device__ int      g_pcol[NE];

__device__ __forceinline__ h4 f2h4(float4 v) {
  return (h4){(_Float16)v.x, (_Float16)v.y, (_Float16)v.z, (_Float16)v.w};
}
__device__ __forceinline__ h8 f2h8(float4 a, float4 b) {
  return (h8){(_Float16)a.x, (_Float16)a.y, (_Float16)a.z, (_Float16)a.w,
              (_Float16)b.x, (_Float16)b.y, (_Float16)b.z, (_Float16)b.w};
}

// -------------------- weight repack (inputs only) --------------------
__global__ __launch_bounds__(256) void cvt_kernel(const float* __restrict__ W1,
                                                  const float* __restrict__ W_hh) {
  const int idx = blockIdx.x * 256 + threadIdx.x;
  const int g = idx >> 6, l = idx & 63;
  const int r16 = l & 15, koff = (l >> 4) * 8;
  const float* src; _Float16* dst;
  if (g < 32) {                                   // W1cf: cf<16, ks<2 (k = 512+...)
    const int cf = g >> 1, ks = g & 1;
    src = &W1[(size_t)(cf * 16 + r16) * DIN + 512 + ks * 32 + koff];
    dst = &g_W1cf[(size_t)(cf * 2 + ks) * 512 + l * 8];
  } else if (g < 288) {                           // W12f: cf<32, ks<8
    const int gg = g - 32, cf = gg >> 3, ks = gg & 7;
    src = (cf < 16) ? &W1[(size_t)(cf * 16 + r16) * DIN + ks * 32 + koff]
                    : &W1[(size_t)((cf - 16) * 16 + r16) * DIN + 256 + ks * 32 + koff];
    dst = &g_W12f[(size_t)(cf * 8 + ks) * 512 + l * 8];
  } else if (g < 544) {                           // Wrzf ks in [8,16): W_hh r,z rows
    const int gg = g - 288, cf = gg >> 3, ks = 8 + (gg & 7);
    const int row = (cf < 16) ? cf * 16 + r16 : 256 + (cf - 16) * 16 + r16;
    src = &W_hh[(size_t)row * HD + (ks - 8) * 32 + koff];
    dst = &g_Wrzf[(size_t)(cf * 16 + ks) * 512 + l * 8];
  } else {                                        // Wnhf: W_hh rows 512..767
    const int gg = g - 544, cf = gg >> 3, ks = gg & 7;
    src = &W_hh[(size_t)(512 + cf * 16 + r16) * HD + ks * 32 + koff];
    dst = &g_Wnhf[(size_t)(cf * 8 + ks) * 512 + l * 8];
  }
#pragma unroll
  for (int j = 0; j < 8; ++j) dst[j] = (_Float16)src[j];
}

// -------------------- Wfold = W_ih @ W2, Wib2 = W_ih @ b2 --------------------
__global__ __launch_bounds__(256) void fold_kernel(const float* __restrict__ W_ih,
                                                   const float* __restrict__ W2,
                                                   const float* __restrict__ b2) {
  const int r = blockIdx.x, c = threadIdx.x;
  const float* wr = W_ih + (size_t)r * HD;
  float acc = 0.f;
  for (int m = 0; m < HD; ++m) acc += wr[m] * W2[(size_t)m * HD + c];
  const int ks = c >> 5, lg = (c >> 3) & 3, j = c & 7;
  const int l = lg * 16 + (r & 15);
  if (r < 512) {
    const int cf = (r < 256) ? (r >> 4) : (16 + ((r - 256) >> 4));
    g_Wrzf[(size_t)((cf * 16 + ks) * 64 + l) * 8 + j] = (_Float16)acc;
  } else {
    const int cf = (r - 512) >> 4;
    g_Wnxf[(size_t)((cf * 8 + ks) * 64 + l) * 8 + j] = (_Float16)acc;
  }
  if (c == 0) {
    float a2 = 0.f;
    for (int m = 0; m < HD; ++m) a2 += wr[m] * b2[m];
    g_Wib2[r] = a2;
  }
}

// -------------------- pre kernel: pre12 = h @ [W1a|W1b]^T --------------------
#define PSTR 264
__global__ __launch_bounds__(256, 4) void pre_kernel(const float* __restrict__ h) {
  __shared__ _Float16 A[32 * PSTR];   // 16.9 KB
  const int t = threadIdx.x, w = t >> 6, l = t & 63;
  const int l15 = l & 15, lg = l >> 4;
  const int nb = blockIdx.x * 32;

  const int row = t >> 3, c8 = t & 7;
#pragma unroll
  for (int i = 0; i < 8; ++i) {
    const int col4 = c8 + i * 8;
    float4 v = ((const float4*)(h + (size_t)(nb + row) * HD))[col4];
    *(h4*)&A[row * PSTR + col4 * 4] = f2h4(v);
  }
  __syncthreads();

  f32x4 acc[2][8];
#pragma unroll
  for (int m = 0; m < 2; ++m)
#pragma unroll
    for (int n = 0; n < 8; ++n) acc[m][n] = (f32x4){0.f, 0.f, 0.f, 0.f};

  for (int ks = 0; ks < 8; ++ks) {
    h8 a[2];
#pragma unroll
    for (int m = 0; m < 2; ++m)
      a[m] = *(const h8*)&A[(m * 16 + l15) * PSTR + ks * 32 + lg * 8];
#pragma unroll
    for (int n = 0; n < 8; ++n) {
      const h8 b = *(const h8*)&g_W12f[(size_t)((w * 8 + n) * 8 + ks) * 512 + l * 8];
#pragma unroll
      for (int m = 0; m < 2; ++m)
        acc[m][n] = __builtin_amdgcn_mfma_f32_16x16x32_f16(a[m], b, acc[m][n], 0, 0, 0);
    }
  }

#pragma unroll
  for (int m = 0; m < 2; ++m)
#pragma unroll
    for (int n = 0; n < 8; ++n) {
      const int col = w * 128 + n * 16 + l15;
#pragma unroll
      for (int r = 0; r < 4; ++r)
        g_pre[(size_t)(nb + m * 16 + lg * 4 + r) * 512 + col] = (_Float16)acc[m][n][r];
    }
}

// -------------------- eterm kernel: eterm = eattr @ W1c^T (dense, streaming) ----
__global__ __launch_bounds__(256) void eterm_kernel(const float* __restrict__ eattr) {
  const int t = threadIdx.x, w = t >> 6, l = t & 63;
  const int l15 = l & 15, lg = l >> 4;
  const int e0 = blockIdx.x * 64;

  f32x4 acc[4][4];
#pragma unroll
  for (int m = 0; m < 4; ++m)
#pragma unroll
    for (int n = 0; n < 4; ++n) acc[m][n] = (f32x4){0.f, 0.f, 0.f, 0.f};

#pragma unroll
  for (int ks = 0; ks < 2; ++ks) {
    h8 a[4], b[4];
#pragma unroll
    for (int m = 0; m < 4; ++m) {
      const float* ep = eattr + (size_t)(e0 + m * 16 + l15) * EDIM + ks * 32 + lg * 8;
      a[m] = f2h8(((const float4*)ep)[0], ((const float4*)ep)[1]);
    }
#pragma unroll
    for (int n = 0; n < 4; ++n)
      b[n] = *(const h8*)&g_W1cf[(size_t)((w * 4 + n) * 2 + ks) * 512 + l * 8];
#pragma unroll
    for (int m = 0; m < 4; ++m)
#pragma unroll
      for (int n = 0; n < 4; ++n)
        acc[m][n] = __builtin_amdgcn_mfma_f32_16x16x32_f16(a[m], b[n], acc[m][n], 0, 0, 0);
  }

#pragma unroll
  for (int m = 0; m < 4; ++m)
#pragma unroll
    for (int r = 0; r < 4; ++r) {
      const int e = e0 + m * 16 + lg * 4 + r;
#pragma unroll
      for (int n = 0; n < 4; ++n)
        g_eterm[(size_t)e * 256 + w * 64 + n * 16 + l15] = (_Float16)acc[m][n][r];
    }
}

// -------------------- CSR build: hist -> scan -> scatter --------------------
__global__ __launch_bounds__(256) void hist_kernel(const int* __restrict__ ei,
                                                   int* __restrict__ deg) {
  const int e = blockIdx.x * 256 + threadIdx.x;
  if (e < NE) atomicAdd(&deg[ei[e]], 1);
}

__global__ __launch_bounds__(512) void scan_kernel(const int* __restrict__ deg) {
  __shared__ int part[512];
  const int t = threadIdx.x;
  const int base = t * 40;
  int loc[40];
  int s = 0;
#pragma unroll
  for (int i = 0; i < 40; ++i) {
    const int idx = base + i;
    const int d = (idx < NN) ? deg[idx] : 0;
    loc[i] = s; s += d;
  }
  part[t] = s;
  __syncthreads();
  for (int off = 1; off < 512; off <<= 1) {
    const int v = (t >= off) ? part[t - off] : 0;
    __syncthreads();
    part[t] += v;
    __syncthreads();
  }
  const int pre = (t == 0) ? 0 : part[t - 1];
#pragma unroll
  for (int i = 0; i < 40; ++i) {
    const int idx = base + i;
    if (idx < NN) { const int v = pre + loc[i]; g_rowptr[idx] = v; g_cursor[idx] = v; }
  }
  if (t == 511) g_rowptr[NN] = part[511];
}

__global__ __launch_bounds__(256) void scatter_kernel(const int* __restrict__ ei) {
  const int e = blockIdx.x * 256 + threadIdx.x;
  if (e < NE) {
    const int r = ei[e];
    const int p = atomicAdd(&g_cursor[r], 1);
    g_perm[p] = e;
    g_pcol[p] = ei[NE + e];
  }
}

// -------------------- agg kernel: register pull-sum per node --------------------
// one wave per node; lane owns cols [l*4, l*4+4)
__global__ __launch_bounds__(256) void agg_kernel(const float* __restrict__ b1,
                                                  float* __restrict__ S) {
  const int t = threadIdx.x, w = t >> 6, l = t & 63;
  const int n = blockIdx.x * 4 + w;
  const int start = g_rowptr[n];
  const int end = g_rowptr[n + 1];

  const h4 p1 = *(const h4*)&g_pre[(size_t)n * 512 + l * 4];
  const f32x4 b1v = *(const f32x4*)&b1[l * 4];
  f32x4 base;
#pragma unroll
  for (int r = 0; r < 4; ++r) base[r] = (float)p1[r] + b1v[r];

  f32x4 acc = (f32x4){0.f, 0.f, 0.f, 0.f};
  for (int i = start; i < end; ++i) {
    const int e = g_perm[i];
    const int c = g_pcol[i];
    const h4 q2 = *(const h4*)&g_pre[(size_t)c * 512 + 256 + l * 4];
    const h4 et = *(const h4*)&g_eterm[(size_t)e * 256 + l * 4];
#pragma unroll
    for (int r = 0; r < 4; ++r) {
      float v = base[r] + (float)q2[r] + (float)et[r];
      acc[r] += v > 0.f ? v : 0.f;
    }
  }
  *(f32x4*)&S[(size_t)n * HD + l * 4] = acc;
}

// -------------------- node kernel: fused W2-fold GRU --------------------
#define ASTRIDE 264
__global__ __launch_bounds__(256, 4) void node_kernel(
    const float* __restrict__ h, const float* __restrict__ S,
    const int* __restrict__ deg,
    const float* __restrict__ b_ih, const float* __restrict__ b_hh,
    float* __restrict__ out)
{
  __shared__ _Float16 A[64 * ASTRIDE];

  const int t = threadIdx.x, w = t >> 6, l = t & 63;
  const int l15 = l & 15, lg = l >> 4;
  const int nb = blockIdx.x * 64;
  const int c0 = blockIdx.y * 64;
  const int cf0 = c0 >> 4;

  f32x4 ar[4], az[4], ax[4], ah[4];
#pragma unroll
  for (int n = 0; n < 4; ++n) {
    ar[n] = (f32x4){0.f, 0.f, 0.f, 0.f}; az[n] = (f32x4){0.f, 0.f, 0.f, 0.f};
    ax[n] = (f32x4){0.f, 0.f, 0.f, 0.f}; ah[n] = (f32x4){0.f, 0.f, 0.f, 0.f};
  }

  const int afrag_base = (w * 16 + l15) * ASTRIDE + lg * 8;

#pragma unroll
  for (int s = 0; s < 2; ++s) {
    __syncthreads();
    const float* src = s == 0 ? S : h;
#pragma unroll
    for (int i = 0; i < 16; ++i) {
      const int e = i * 4 + w;
      int node = nb + e; if (node >= NN) node = NN - 1;
      float4 v = ((const float4*)(src + (size_t)node * HD))[l];
      *(h4*)&A[e * ASTRIDE + l * 4] = f2h4(v);
    }
    __syncthreads();
    for (int ks = 0; ks < 8; ++ks) {
      const int ksg = s * 8 + ks;
      const h8 a = *(const h8*)&A[afrag_base + ks * 32];
      h8 br[4], bz[4], bn[4];
#pragma unroll
      for (int n = 0; n < 4; ++n) {
        br[n] = *(const h8*)&g_Wrzf[(size_t)(((cf0 + n) * 16 + ksg) * 64 + l) * 8];
        bz[n] = *(const h8*)&g_Wrzf[(size_t)(((16 + cf0 + n) * 16 + ksg) * 64 + l) * 8];
        bn[n] = (s == 0)
          ? *(const h8*)&g_Wnxf[(size_t)(((cf0 + n) * 8 + ks) * 64 + l) * 8]
          : *(const h8*)&g_Wnhf[(size_t)(((cf0 + n) * 8 + ks) * 64 + l) * 8];
      }
#pragma unroll
      for (int n = 0; n < 4; ++n) {
        ar[n] = __builtin_amdgcn_mfma_f32_16x16x32_f16(a, br[n], ar[n], 0, 0, 0);
        az[n] = __builtin_amdgcn_mfma_f32_16x16x32_f16(a, bz[n], az[n], 0, 0, 0);
        if (s == 0) ax[n] = __builtin_amdgcn_mfma_f32_16x16x32_f16(a, bn[n], ax[n], 0, 0, 0);
        else        ah[n] = __builtin_amdgcn_mfma_f32_16x16x32_f16(a, bn[n], ah[n], 0, 0, 0);
      }
    }
  }

#pragma unroll
  for (int r = 0; r < 4; ++r) {
    const int node = nb + w * 16 + lg * 4 + r;
    if (node >= NN) continue;
    const float df = (float)deg[node];
#pragma unroll
    for (int n = 0; n < 4; ++n) {
      const int c = c0 + n * 16 + l15;
      const float rg = 1.f / (1.f + __expf(-(ar[n][r] + df * g_Wib2[c] + b_ih[c] + b_hh[c])));
      const float zg = 1.f / (1.f + __expf(-(az[n][r] + df * g_Wib2[HD + c] + b_ih[HD + c] + b_hh[HD + c])));
      const float ng = tanhf(ax[n][r] + df * g_Wib2[2 * HD + c] + b_ih[2 * HD + c]
                             + rg * (ah[n][r] + b_hh[2 * HD + c]));
      const float hv = h[(size_t)node * HD + c];
      out[(size_t)node * HD + c] = (1.f - zg) * ng + zg * hv;
    }
  }
}

extern "C" void kernel_launch(void* const* d_in, const int* in_sizes, int n_in,
                              void* d_out, int out_size, void* d_ws, size_t ws_size,
                              hipStream_t stream)
{
  const float* h     = (const float*)d_in[0];
  const int*   ei    = (const int*)d_in[1];
  const float* eattr = (const float*)d_in[2];
  const float* W1    = (const float*)d_in[3];
  const float* b1    = (const float*)d_in[4];
  const float* W2    = (const float*)d_in[5];
  const float* b2    = (const float*)d_in[6];
  const float* W_ih  = (const float*)d_in[7];
  const float* b_ih  = (const float*)d_in[8];
  const float* W_hh  = (const float*)d_in[9];
  const float* b_hh  = (const float*)d_in[10];
  float* out = (float*)d_out;

  float* S  = (float*)d_ws;                                 // [NN][HD] f32
  int*  deg = (int*)((char*)d_ws + (size_t)NN * HD * 4);    // [NN] i32

  hipMemsetAsync(d_ws, 0, (size_t)NN * HD * 4 + (size_t)NN * 4, stream);
  cvt_kernel<<<168, 256, 0, stream>>>(W1, W_hh);
  fold_kernel<<<768, 256, 0, stream>>>(W_ih, W2, b2);
  pre_kernel<<<NN / 32, 256, 0, stream>>>(h);
  eterm_kernel<<<NE / 64, 256, 0, stream>>>(eattr);
  hist_kernel<<<(NE + 255) / 256, 256, 0, stream>>>(ei, deg);
  scan_kernel<<<1, 512, 0, stream>>>(deg);
  scatter_kernel<<<(NE + 255) / 256, 256, 0, stream>>>(ei);
  agg_kernel<<<NN / 4, 256, 0, stream>>>(b1, S);
  node_kernel<<<dim3((NN + 63) / 64, HD / 64), 256, 0, stream>>>(h, S, deg, b_ih, b_hh, out);
}